// Round 9
// baseline (148.865 us; speedup 1.0000x reference)
//
#include <hip/hip_runtime.h>

#define CUTOFF_F 6.0f
#define PI_F 3.14159265358979323846f
#define CAP 112     // bucket capacity per dest; mean ~61, max ~96 with this fixed input
#define EXCAP 8192  // extras list capacity (overflow fallback; statistically never used)

typedef __fp16   fp16x2 __attribute__((ext_vector_type(2)));  // builtin ABI type (cvt_pkrtz/fdot2)
typedef _Float16 h2f    __attribute__((ext_vector_type(2)));  // arithmetic type (native pk ops)

union hcv { unsigned u; fp16x2 b; h2f a; };
__device__ __forceinline__ unsigned as_u(h2f x)   { hcv c; c.a = x; return c.u; }
__device__ __forceinline__ h2f      u2a(unsigned v){ hcv c; c.u = v; return c.a; }
__device__ __forceinline__ fp16x2   u2b(unsigned v){ hcv c; c.u = v; return c.b; }

__device__ __forceinline__ unsigned pk2(float a, float b) {
  hcv c; c.b = __builtin_amdgcn_cvt_pkrtz(a, b); return c.u;
}
__device__ __forceinline__ float f16bits(unsigned v) {
  union { unsigned short u; __fp16 h; } cv; cv.u = (unsigned short)v; return (float)cv.h;
}

// Packed f16 dot with f32 accumulate: v_dot2_f32_f16 when available.
__device__ __forceinline__ float FDOT2(unsigned a, unsigned b, float c) {
#if defined(__has_builtin) && __has_builtin(__builtin_amdgcn_fdot2)
  return __builtin_amdgcn_fdot2(u2b(a), u2b(b), c, false);
#else
  h2f x = u2a(a), y = u2a(b);
  return fmaf((float)x.x, (float)y.x, fmaf((float)x.y, (float)y.y, c));
#endif
}

template<int CTRL>
__device__ __forceinline__ float dpp_add(float x) {
  int y = __builtin_amdgcn_update_dpp(0, __float_as_int(x), CTRL, 0xf, 0xf, true);
  return x + __int_as_float(y);
}
// Sum across 64 lanes; result valid in lane 63 only. Pure VALU (DPP), no LDS.
__device__ __forceinline__ float wave_sum63(float x) {
  x = dpp_add<0x111>(x);  // row_shr:1
  x = dpp_add<0x112>(x);  // row_shr:2
  x = dpp_add<0x114>(x);  // row_shr:4
  x = dpp_add<0x118>(x);  // row_shr:8
  x = dpp_add<0x142>(x);  // row_bcast:15
  x = dpp_add<0x143>(x);  // row_bcast:31 -> lane63 = total
  return x;
}

__device__ __forceinline__ float fast_tanh(float x) {
  float e = __expf(2.0f * x);
  return 1.0f - 2.0f * __builtin_amdgcn_rcpf(e + 1.0f);
}

__global__ __launch_bounds__(256) void field_zero(
    int* __restrict__ counts, int* __restrict__ ecount, int bn) {
  const int i = blockIdx.x * 256 + threadIdx.x;
  if (i < bn) counts[i] = 0;
  if (i == 0) ecount[0] = 0;
}

__global__ __launch_bounds__(256) void field_main(
    const int* __restrict__ element_map,
    const int* __restrict__ neighbor_indices,
    const int* __restrict__ neighbor_types,
    const float4* __restrict__ neighbor_vectors,
    const float* __restrict__ type_embed,
    const float* __restrict__ elem_bias,
    const float* __restrict__ W1,
    const float* __restrict__ b1,
    const float* __restrict__ W2,
    const float* __restrict__ b2,
    const float* __restrict__ W3,
    const float* __restrict__ b3,
    float* __restrict__ outEi,     // [B*n]
    int* __restrict__ counts,      // ws: [B*n] (zeroed)
    int* __restrict__ ecount,      // ws: overflow counter (zeroed)
    float4* __restrict__ extras,   // ws: [EXCAP] overflow payloads
    float4* __restrict__ bucket,   // ws: [B*n*CAP] payload 6xf16 {g3, r3}
    float* __restrict__ partials,  // ws: [gridDim.x*10]
    int n)
{
  // LDS budget ~11.5 KB/block (occupancy: effective pool appears ~64KB -> 5 blocks/CU)
  __shared__ uint4  sW1f[16];       // fwd: per dim-pair {a01|k0, a23|k0, a01|k1, a23|k1}
  __shared__ uint4  sW1b[16];       // bwd: per k-pair {W1[a][2p],W1[a][2p+1]} a=0..3
  __shared__ unsigned sW2h[16*33];  // h2: [p][kd] = pk2(W2[2p][kd], W2[2p+1][kd]), stride 33
  __shared__ unsigned sW2d[32*17];  // dg: [kd][p] = pk2(W2[kd][2p], W2[kd][2p+1]), stride 17
  __shared__ float2 sbte2[3][16];   // bias pairs: b1 + type_embed
  __shared__ float  sW3[32];
  __shared__ float  sb2[32];
  __shared__ float  sElemBias[3];
  __shared__ float  sb3;
  __shared__ float  blkEi[4];
  __shared__ float  blkVir[4][9];
  __shared__ unsigned hb[4][64][5]; // 4-pass transpose buf: 4 packed dims + 1 pad (5.1 KB)
  __shared__ unsigned sgp[4][16];   // packed g pairs (f16)
  __shared__ unsigned stl[4][16];   // packed t pairs
  __shared__ unsigned sdg[4][16];   // packed dg/m pairs

  const int tid = threadIdx.x;

  // ---- cooperative LDS staging (packed f16 weights) ----
  if (tid < 32) { sW3[tid] = W3[tid]; sb2[tid] = b2[tid]; }
  if (tid < 16) {
    const int k0 = 2*tid, k1 = 2*tid + 1;
    sW1f[tid] = make_uint4(pk2(W1[k0],    W1[32+k0]),
                           pk2(W1[64+k0], W1[96+k0]),
                           pk2(W1[k1],    W1[32+k1]),
                           pk2(W1[64+k1], W1[96+k1]));
  } else if (tid < 32) {
    const int p = tid - 16, k0 = 2*p, k1 = 2*p + 1;
    sW1b[p] = make_uint4(pk2(W1[k0],    W1[k1]),
                         pk2(W1[32+k0], W1[32+k1]),
                         pk2(W1[64+k0], W1[64+k1]),
                         pk2(W1[96+k0], W1[96+k1]));
  } else if (tid < 80) {
    const int i = tid - 32, t = i >> 4, pp = i & 15;
    sbte2[t][pp] = make_float2(b1[2*pp]   + type_embed[t*32 + 2*pp],
                               b1[2*pp+1] + type_embed[t*32 + 2*pp+1]);
  } else if (tid == 80) {
    sb3 = b3[0];
  } else if (tid < 84) {
    sElemBias[tid - 81] = elem_bias[tid - 81];
  }
  for (int i = tid; i < 512; i += 256) {
    const int p = i >> 5, kd = i & 31;
    sW2h[p*33 + kd] = pk2(W2[(2*p)*32 + kd], W2[(2*p+1)*32 + kd]);
    const int l = i >> 4, pp = i & 15;
    sW2d[l*17 + pp] = pk2(W2[l*32 + 2*pp], W2[l*32 + 2*pp + 1]);
  }
  __syncthreads();

  const int wave = tid >> 6;
  const int lane = tid & 63;
  const int atom = blockIdx.x * 4 + wave;  // [0, B*n)
  const int bb = atom / n;

  const int base = atom * 64 + lane;  // neighbor slot
  const int idx = neighbor_indices[base];
  const int dest = bb * n + idx;
  const int em = element_map[atom];   // hoisted

  int pos = 0;
  const bool real = (idx < n);
  if (real) pos = atomicAdd(&counts[dest], 1);  // latency hides under the MLP

  const float4 nv = neighbor_vectors[base];
  const float rx = nv.y, ry = nv.z, rz = nv.w;
  const int typ = neighbor_types[base];

  // ---- s(d), s'(d) (f32) ----
  const float d2 = rx * rx + ry * ry + rz * rz;
  const float d = sqrtf(d2);
  const float invd = (d > 0.0f) ? __builtin_amdgcn_rcpf(d) : 0.0f;
  float s, sp;
  if (d < CUTOFF_F) {
    const float arg = d * (PI_F / CUTOFF_F);
    const float cs = __cosf(arg);
    const float sn = __sinf(arg);
    const float e = __expf(-d);
    const float fc = 0.5f * (cs + 1.0f);
    const float fcp = -(0.5f * PI_F / CUTOFF_F) * sn;
    s = e * fc;
    sp = e * (fcp - fc);
  } else {
    s = 0.0f;
    sp = 0.0f;
  }
  const float f1 = s * rx, f2 = s * ry, f3 = s * rz;
  const unsigned sf01 = pk2(s, f1);
  const unsigned f23  = pk2(f2, f3);

  // ---- forward MLP (fdot2) + 4-pass packed-f16 transpose ----
  unsigned hpz[16];                 // h as packed f16 pairs (regs)
  const int pair2 = lane & 3;       // transpose: dim-pair handled
  const int grp   = lane >> 2;      //   neighbor quartet summed

#pragma unroll
  for (int P = 0; P < 4; ++P) {
#pragma unroll
    for (int e = 0; e < 4; ++e) {
      const int p = 4*P + e;        // global dim-pair
      const uint4 wq = sW1f[p];
      const float2 bt = sbte2[typ][p];
      float pre0 = FDOT2(sf01, wq.x, bt.x);
      pre0 = FDOT2(f23, wq.y, pre0);
      float pre1 = FDOT2(sf01, wq.z, bt.y);
      pre1 = FDOT2(f23, wq.w, pre1);
      const unsigned hp = pk2(fast_tanh(pre0), fast_tanh(pre1));
      hpz[p] = hp;
      hb[wave][lane][e] = hp;
    }
    // packed transpose-reduce: sum dim-pair over 64 neighbors (f16 pk adds)
    h2f acc = u2a(hb[wave][grp*4 + 0][pair2]);
    acc = acc + u2a(hb[wave][grp*4 + 1][pair2]);
    acc = acc + u2a(hb[wave][grp*4 + 2][pair2]);
    acc = acc + u2a(hb[wave][grp*4 + 3][pair2]);
    acc = acc + u2a((unsigned)__shfl_xor((int)as_u(acc), 4));
    acc = acc + u2a((unsigned)__shfl_xor((int)as_u(acc), 8));
    acc = acc + u2a((unsigned)__shfl_xor((int)as_u(acc), 16));
    acc = acc + u2a((unsigned)__shfl_xor((int)as_u(acc), 32));
    if (lane < 4) {
      const h2f g2 = acc * (_Float16)(1.0f / 64.0f);
      sgp[wave][4*P + lane] = as_u(g2);
    }
  }

  // ---- h2: half-split fdot2 (lane kd, half hh covers 8 of 16 pairs) ----
  const int kd = lane & 31;
  const int hh = lane >> 5;
  float acc0 = 0.0f, acc1 = 0.0f;
#pragma unroll
  for (int j = 0; j < 8; j += 2) {
    const int p = hh*8 + j;
    acc0 = FDOT2(sgp[wave][p],     sW2h[p*33 + kd],       acc0);
    acc1 = FDOT2(sgp[wave][p + 1], sW2h[(p + 1)*33 + kd], acc1);
  }
  float accs = acc0 + acc1;
  accs += __shfl_xor(accs, 32);
  accs += sb2[kd];
  const float h2v = fast_tanh(accs);
  const float tl = (1.0f - h2v * h2v) * sW3[kd];
  const float tlo = __shfl_xor(tl, 1);
  if (lane < 32 && !(kd & 1)) stl[wave][kd >> 1] = pk2(tl, tlo);

  // ---- dg/m: half-split fdot2 ----
  float d0 = 0.0f, d1 = 0.0f;
#pragma unroll
  for (int j = 0; j < 8; j += 2) {
    const int p = hh*8 + j;
    d0 = FDOT2(stl[wave][p],     sW2d[kd*17 + p],     d0);
    d1 = FDOT2(stl[wave][p + 1], sW2d[kd*17 + p + 1], d1);
  }
  float dgs = (d0 + d1);
  dgs += __shfl_xor(dgs, 32);
  dgs *= (1.0f / 64.0f);
  const float dgo = __shfl_xor(dgs, 1);
  if (lane < 32 && !(kd & 1)) sdg[wave][kd >> 1] = pk2(dgs, dgo);

  // ---- Ei partial (each dim twice across 64 lanes -> x0.5 later) ----
  const float pEi = h2v * sW3[kd];

  // ---- backward to feat: packed dpre + fdot2 ----
  const h2f one16 = {(_Float16)1.0f, (_Float16)1.0f};
  float q0 = 0.0f, q1 = 0.0f, q2 = 0.0f, q3 = 0.0f;
#pragma unroll
  for (int p = 0; p < 16; ++p) {
    const h2f hp = u2a(hpz[p]);
    const h2f omh = one16 - hp * hp;           // v_pk ops
    const h2f dpre = u2a(sdg[wave][p]) * omh;  // dg/m * (1-h^2), packed
    const uint4 wq = sW1b[p];
    const unsigned du = as_u(dpre);
    q0 = FDOT2(du, wq.x, q0);
    q1 = FDOT2(du, wq.y, q1);
    q2 = FDOT2(du, wq.z, q2);
    q3 = FDOT2(du, wq.w, q3);
  }

  const float common = sp * invd * (q0 + q1 * rx + q2 * ry + q3 * rz);
  const float gx = fmaf(common, rx, s * q1);
  const float gy = fmaf(common, ry, s * q2);
  const float gz = fmaf(common, rz, s * q3);

  // ---- deposit payload {g3,r3} as 6xf16 in one 16B slot ----
  if (real) {
    float4 pay;
    pay.x = __uint_as_float(pk2(gx, gy));
    pay.y = __uint_as_float(pk2(gz, rx));
    pay.z = __uint_as_float(pk2(ry, rz));
    if (pos < CAP) {
      pay.w = 0.0f;
      bucket[(size_t)dest * CAP + pos] = pay;
    } else {
      const int ep = atomicAdd(ecount, 1);
      if (ep < EXCAP) { pay.w = __int_as_float(dest); extras[ep] = pay; }
    }
  }

  // ---- wave reductions via DPP: self-force, virial, Ei ----
  float sfx = wave_sum63(gx);
  float sfy = wave_sum63(gy);
  float sfz = wave_sum63(gz);
  float vr0 = wave_sum63(rx * gx), vr1 = wave_sum63(rx * gy), vr2 = wave_sum63(rx * gz);
  float vr3 = wave_sum63(ry * gx), vr4 = wave_sum63(ry * gy), vr5 = wave_sum63(ry * gz);
  float vr6 = wave_sum63(rz * gx), vr7 = wave_sum63(rz * gy), vr8 = wave_sum63(rz * gz);
  float psum = wave_sum63(pEi) * 0.5f;

  if (lane == 63) {
    const float Ei_val = psum + sb3 + sElemBias[em];
    outEi[atom] = Ei_val;
    blkEi[wave] = Ei_val;
    blkVir[wave][0] = vr0; blkVir[wave][1] = vr1; blkVir[wave][2] = vr2;
    blkVir[wave][3] = vr3; blkVir[wave][4] = vr4; blkVir[wave][5] = vr5;
    blkVir[wave][6] = vr6; blkVir[wave][7] = vr7; blkVir[wave][8] = vr8;
    // self-force as bucket entry {-sf, r=0}
    float4 pay;
    pay.x = __uint_as_float(pk2(-sfx, -sfy));
    pay.y = __uint_as_float(pk2(-sfz, 0.0f));
    pay.z = 0.0f;
    const int spos = atomicAdd(&counts[atom], 1);
    if (spos < CAP) {
      pay.w = 0.0f;
      bucket[(size_t)atom * CAP + spos] = pay;
    } else {
      const int ep = atomicAdd(ecount, 1);
      if (ep < EXCAP) { pay.w = __int_as_float(atom); extras[ep] = pay; }
    }
  }

  __syncthreads();
  if (tid < 9) {
    partials[blockIdx.x * 10 + tid] =
        blkVir[0][tid] + blkVir[1][tid] + blkVir[2][tid] + blkVir[3][tid];
  } else if (tid == 9) {
    partials[blockIdx.x * 10 + 9] = blkEi[0] + blkEi[1] + blkEi[2] + blkEi[3];
  }
}

// One wave per destination atom; plain coalesced stores. Blocks 0/1 fold in
// the Etot/virial reduction.
__global__ __launch_bounds__(256) void field_gather(
    const int* __restrict__ counts,
    const int* __restrict__ ecount,
    const float4* __restrict__ extras,
    const float4* __restrict__ bucket,
    const float* __restrict__ partials,
    float* __restrict__ outForce,
    float* __restrict__ outAV,
    float* __restrict__ outEtot,
    float* __restrict__ outVirial,
    int half)
{
  __shared__ float sf[4][12];
  __shared__ float sacc[4][10];
  const int tid = threadIdx.x;
  const int wave = tid >> 6;
  const int lane = tid & 63;
  const int dest = blockIdx.x * 4 + wave;

  const int rawcnt = counts[dest];
  const int cnt = (rawcnt > CAP) ? CAP : rawcnt;
  const int ec0 = *ecount;

  float fx = 0.0f, fy = 0.0f, fz = 0.0f;
  float a0 = 0, a1 = 0, a2 = 0, a3 = 0, a4 = 0, a5 = 0, a6 = 0, a7 = 0, a8 = 0;

#pragma unroll 2
  for (int l = lane; l < cnt; l += 64) {
    const float4 pay = bucket[(size_t)dest * CAP + l];
    const unsigned w0 = __float_as_uint(pay.x);
    const unsigned w1 = __float_as_uint(pay.y);
    const unsigned w2 = __float_as_uint(pay.z);
    const float gx = f16bits(w0), gy = f16bits(w0 >> 16);
    const float gz = f16bits(w1), rx = f16bits(w1 >> 16);
    const float ry = f16bits(w2), rz = f16bits(w2 >> 16);
    fx -= gx; fy -= gy; fz -= gz;
    a0 = fmaf(rx, gx, a0); a1 = fmaf(rx, gy, a1); a2 = fmaf(rx, gz, a2);
    a3 = fmaf(ry, gx, a3); a4 = fmaf(ry, gy, a4); a5 = fmaf(ry, gz, a5);
    a6 = fmaf(rz, gx, a6); a7 = fmaf(rz, gy, a7); a8 = fmaf(rz, gz, a8);
  }

  if (ec0 > 0) {
    const int ec = (ec0 < EXCAP) ? ec0 : EXCAP;
    for (int t = lane; t < ec; t += 64) {
      const float4 ex = extras[t];
      if (__float_as_int(ex.w) == dest) {
        const unsigned w0 = __float_as_uint(ex.x);
        const unsigned w1 = __float_as_uint(ex.y);
        const unsigned w2 = __float_as_uint(ex.z);
        const float gx = f16bits(w0), gy = f16bits(w0 >> 16);
        const float gz = f16bits(w1), rx = f16bits(w1 >> 16);
        const float ry = f16bits(w2), rz = f16bits(w2 >> 16);
        fx -= gx; fy -= gy; fz -= gz;
        a0 = fmaf(rx, gx, a0); a1 = fmaf(rx, gy, a1); a2 = fmaf(rx, gz, a2);
        a3 = fmaf(ry, gx, a3); a4 = fmaf(ry, gy, a4); a5 = fmaf(ry, gz, a5);
        a6 = fmaf(rz, gx, a6); a7 = fmaf(rz, gy, a7); a8 = fmaf(rz, gz, a8);
      }
    }
  }

  fx = wave_sum63(fx); fy = wave_sum63(fy); fz = wave_sum63(fz);
  a0 = wave_sum63(a0); a1 = wave_sum63(a1); a2 = wave_sum63(a2);
  a3 = wave_sum63(a3); a4 = wave_sum63(a4); a5 = wave_sum63(a5);
  a6 = wave_sum63(a6); a7 = wave_sum63(a7); a8 = wave_sum63(a8);

  if (lane == 63) {
    sf[wave][0] = fx; sf[wave][1] = fy; sf[wave][2] = fz;
    sf[wave][3] = a0; sf[wave][4] = a1; sf[wave][5] = a2;
    sf[wave][6] = a3; sf[wave][7] = a4; sf[wave][8] = a5;
    sf[wave][9] = a6; sf[wave][10] = a7; sf[wave][11] = a8;
  }
  __syncthreads();

  const int d0 = blockIdx.x * 4;
  if (tid < 12) {
    outForce[(size_t)d0 * 3 + tid] = sf[tid / 3][tid % 3];
  } else if (tid >= 64 && tid < 100) {
    const int t = tid - 64;
    outAV[(size_t)d0 * 9 + t] = sf[t / 9][3 + t % 9];
  }

  if (blockIdx.x < 2) {
    const int b = blockIdx.x;
    float acc[10] = {0, 0, 0, 0, 0, 0, 0, 0, 0, 0};
    for (int r = b * half + tid; r < (b + 1) * half; r += 256) {
#pragma unroll
      for (int t = 0; t < 10; ++t) acc[t] += partials[r * 10 + t];
    }
#pragma unroll
    for (int t = 0; t < 10; ++t) acc[t] = wave_sum63(acc[t]);
    if (lane == 63) {
#pragma unroll
      for (int t = 0; t < 10; ++t) sacc[wave][t] = acc[t];
    }
    __syncthreads();
    if (tid < 9) {
      outVirial[b * 9 + tid] = sacc[0][tid] + sacc[1][tid] + sacc[2][tid] + sacc[3][tid];
    } else if (tid == 9) {
      outEtot[b] = sacc[0][9] + sacc[1][9] + sacc[2][9] + sacc[3][9];
    }
  }
}

extern "C" void kernel_launch(void* const* d_in, const int* in_sizes, int n_in,
                              void* d_out, int out_size, void* d_ws, size_t ws_size,
                              hipStream_t stream) {
  const int* element_map        = (const int*)d_in[0];
  const int* neighbor_indices   = (const int*)d_in[2];
  const int* neighbor_types     = (const int*)d_in[3];
  const float4* neighbor_vectors = (const float4*)d_in[4];
  const float* type_embed = (const float*)d_in[6];
  const float* elem_bias  = (const float*)d_in[7];
  const float* W1 = (const float*)d_in[8];
  const float* b1 = (const float*)d_in[9];
  const float* W2 = (const float*)d_in[10];
  const float* b2 = (const float*)d_in[11];
  const float* W3 = (const float*)d_in[12];
  const float* b3 = (const float*)d_in[13];

  const int B = 2;
  const int bn = in_sizes[0];
  const int n = bn / B;
  const int nblk = bn / 4;

  float* out = (float*)d_out;
  float* outEtot   = out;
  float* outEi     = outEtot + B;
  float* outForce  = outEi + bn;
  float* outVirial = outForce + (size_t)bn * 3;
  float* outAV     = outVirial + (size_t)B * 9;

  // ws layout: counts | ecount(16B) | extras | partials | bucket
  char* ws = (char*)d_ws;
  int* counts = (int*)ws;
  size_t countBytes = (size_t)bn * sizeof(int);
  int* ecount = (int*)(ws + countBytes);
  size_t ecountBytes = 16;
  float4* extras = (float4*)(ws + countBytes + ecountBytes);
  size_t extrasBytes = (size_t)EXCAP * sizeof(float4);
  float* partials = (float*)(ws + countBytes + ecountBytes + extrasBytes);
  size_t partialBytes = (size_t)nblk * 10 * sizeof(float);
  float4* bucket = (float4*)(ws + countBytes + ecountBytes + extrasBytes + partialBytes);

  dim3 block(256);
  hipLaunchKernelGGL(field_zero, dim3((bn + 255) / 256), block, 0, stream,
                     counts, ecount, bn);
  hipLaunchKernelGGL(field_main, dim3(nblk), block, 0, stream,
                     element_map, neighbor_indices, neighbor_types,
                     neighbor_vectors, type_embed, elem_bias,
                     W1, b1, W2, b2, W3, b3,
                     outEi, counts, ecount, extras, bucket, partials, n);
  hipLaunchKernelGGL(field_gather, dim3(nblk), block, 0, stream,
                     counts, ecount, extras, bucket, partials,
                     outForce, outAV, outEtot, outVirial, nblk / B);
}